// Round 9
// baseline (616.050 us; speedup 1.0000x reference)
//
#include <hip/hip_runtime.h>
#include <hip/hip_bf16.h>

#define N_NODES 50000
#define N_EDGES 800000
#define DIM 128
#define N_LAYERS 5
#define BN_EPS 1e-3f
#define KBUK 4
#define BUCKET 12500                       // N_NODES / KBUK
#define NB2 (N_NODES * KBUK)               // 200000 (node,bucket) cells
#define NBLK2 ((NB2 + 255) / 256)          // 782
#define POOL_WAVES 8192                    // 2048 blocks x 4 waves, all co-resident
#define NPW 7                              // ceil(N_NODES / POOL_WAVES)

typedef __attribute__((ext_vector_type(8))) short bf16x8;
typedef __attribute__((ext_vector_type(4))) float f32x4;
typedef __attribute__((ext_vector_type(4))) unsigned int u32x4;
typedef __attribute__((ext_vector_type(2))) unsigned int u32x2;

__device__ __forceinline__ unsigned short f2bf(float f) {
    unsigned int v = __builtin_bit_cast(unsigned int, f);
    v += 0x7fffu + ((v >> 16) & 1u);
    return (unsigned short)(v >> 16);
}
__device__ __forceinline__ float bflo(unsigned int v) {
    return __builtin_bit_cast(float, v << 16);
}
__device__ __forceinline__ float bfhi(unsigned int v) {
    return __builtin_bit_cast(float, v & 0xffff0000u);
}

// ---- setup kernels -------------------------------------------------------

// copy x -> out chunk 0 (fp32) + hb0 (bf16 shadow); also zero cnt2[]
__global__ void init_zero_kernel(const float* __restrict__ x, float* __restrict__ out,
                                 unsigned short* __restrict__ hb, int* __restrict__ cnt2) {
    int t = blockIdx.x * blockDim.x + threadIdx.x;
    if (t < (N_NODES * DIM) / 4) {
        f32x4 v = ((const f32x4*)x)[t];
        __builtin_nontemporal_store(v, (f32x4*)out + t);
        unsigned short u[4] = {f2bf(v.x), f2bf(v.y), f2bf(v.z), f2bf(v.w)};
        *(u32x2*)(hb + t * 4) = *(u32x2*)u;
    }
    int z = t - (N_NODES * DIM) / 4;
    if (z >= 0 && z < NB2) cnt2[z] = 0;
}

// histogram over (dst, src-bucket) cells
__global__ void hist_kernel(const int* __restrict__ src, const int* __restrict__ dst,
                            int* __restrict__ cnt2) {
    int e = blockIdx.x * blockDim.x + threadIdx.x;
    if (e < N_EDGES) {
        int b = src[e] / BUCKET;
        atomicAdd(&cnt2[dst[e] * KBUK + b], 1);
    }
}

// parallel scan over NB2 cells, 3 dispatches
__global__ __launch_bounds__(256) void scanA_kernel(const int* __restrict__ cnt2,
                                                    int* __restrict__ blocksum) {
    const int tid = threadIdx.x, lane = tid & 63, wave = tid >> 6;
    int i = blockIdx.x * 256 + tid;
    int v = (i < NB2) ? cnt2[i] : 0;
#pragma unroll
    for (int off = 1; off < 64; off <<= 1) v += __shfl_xor(v, off, 64);
    __shared__ int ws[4];
    if (lane == 0) ws[wave] = v;
    __syncthreads();
    if (tid == 0) blocksum[blockIdx.x] = ws[0] + ws[1] + ws[2] + ws[3];
}

__global__ __launch_bounds__(1024) void scanB_kernel(int* __restrict__ blocksum,
                                                     int* __restrict__ rs2) {
    __shared__ int s[1024];
    const int tid = threadIdx.x;
    int v = (tid < NBLK2) ? blocksum[tid] : 0;
    s[tid] = v;
    __syncthreads();
#pragma unroll
    for (int off = 1; off < 1024; off <<= 1) {
        int t = (tid >= off) ? s[tid - off] : 0;
        __syncthreads();
        s[tid] += t;
        __syncthreads();
    }
    if (tid < NBLK2) blocksum[tid] = s[tid] - v;  // exclusive block offset
    if (tid == 0) rs2[NB2] = N_EDGES;
}

__global__ __launch_bounds__(256) void scanC_kernel(const int* __restrict__ cnt2,
                                                    const int* __restrict__ blockoff,
                                                    int* __restrict__ rs2,
                                                    int* __restrict__ cursor2) {
    const int tid = threadIdx.x, lane = tid & 63, wave = tid >> 6;
    int i = blockIdx.x * 256 + tid;
    int v = (i < NB2) ? cnt2[i] : 0;
    int x = v;
#pragma unroll
    for (int off = 1; off < 64; off <<= 1) {
        int t = __shfl_up(x, off, 64);
        if (lane >= off) x += t;
    }
    __shared__ int ws[4];
    if (lane == 63) ws[wave] = x;
    __syncthreads();
    int woff = 0;
    if (wave > 0) woff += ws[0];
    if (wave > 1) woff += ws[1];
    if (wave > 2) woff += ws[2];
    int excl = blockoff[blockIdx.x] + woff + x - v;
    if (i < NB2) { rs2[i] = excl; cursor2[i] = excl; }
}

__global__ void fill_kernel(const int* __restrict__ src, const int* __restrict__ dst,
                            int* __restrict__ cursor2, int* __restrict__ col) {
    int e = blockIdx.x * blockDim.x + threadIdx.x;
    if (e < N_EDGES) {
        int s = src[e];
        int b = s / BUCKET;
        int pos = atomicAdd(&cursor2[dst[e] * KBUK + b], 1);
        col[pos] = s;
    }
}

// pack W1/W2 (fp32->bf16) into B-fragment order + fold BN scale/shift
__global__ void prep_kernel(const float* __restrict__ W1, const float* __restrict__ W2,
                            unsigned short* __restrict__ wp,
                            const float* __restrict__ gamma, const float* __restrict__ beta,
                            const float* __restrict__ mean, const float* __restrict__ var,
                            float* __restrict__ scale, float* __restrict__ shift) {
    int t = blockIdx.x * blockDim.x + threadIdx.x;
    if (t < N_LAYERS * 2 * 2048) {
        int mat = t >> 11;
        int r = t & 2047;
        int ks = r >> 9, nt = (r >> 6) & 7, lane = r & 63;
        int layer = mat >> 1;
        const float* W = ((mat & 1) ? W2 : W1) + layer * DIM * DIM;
        int n = nt * 16 + (lane & 15);
        int kb = ks * 32 + (lane >> 4) * 8;
        unsigned short u[8];
#pragma unroll
        for (int j = 0; j < 8; j++) u[j] = f2bf(W[(kb + j) * DIM + n]);
        *(u32x4*)(wp + (size_t)mat * 16384 + ((ks * 8 + nt) * 64 + lane) * 8) = *(u32x4*)u;
    }
    int i = t - N_LAYERS * 2 * 2048;
    if (i >= 0 && i < N_LAYERS * DIM) {
        float sc = gamma[i] * rsqrtf(var[i] + BN_EPS);
        scale[i] = sc;
        shift[i] = beta[i] - mean[i] * sc;
    }
}

// ---- per-layer kernels ---------------------------------------------------

// cache-blocked gather pooling (soft-synced source buckets).
// All 8192 waves are co-resident; each owns 7 interleaved nodes with fp32
// accumulators in registers. Bucket loop is outermost, so the whole grid
// gathers from the SAME 3.2MB source slice at a time -> slice resident in
// every XCD's L2; fabric traffic drops to the one-time warm fill.
// Request shape is the proven-optimal one: 64 lanes x 4B = one coalesced
// 256B row per instruction. Masked lanes clamp to an in-bucket index.
__global__ __launch_bounds__(256) void pool_kernel(const unsigned short* __restrict__ hb,
                                                   const int* __restrict__ rs2,
                                                   const int* __restrict__ col,
                                                   const float* __restrict__ eps_l,
                                                   unsigned short* __restrict__ pooled_b) {
    const int wave = threadIdx.x >> 6, lane = threadIdx.x & 63;
    const int wid = blockIdx.x * 4 + wave;
    const float ev = 1.0f + eps_l[0];
    const int c2 = lane * 2;

    float a0[NPW], a1[NPW];
#pragma unroll
    for (int i = 0; i < NPW; i++) {
        int n = wid + POOL_WAVES * i;
        if (n < N_NODES) {
            unsigned int sv = *(const unsigned int*)(hb + (size_t)n * DIM + c2);
            a0[i] = ev * bflo(sv);
            a1[i] = ev * bfhi(sv);
        } else {
            a0[i] = 0.f; a1[i] = 0.f;
        }
    }

    for (int k = 0; k < KBUK; k++) {
#pragma unroll
        for (int i = 0; i < NPW; i++) {
            int n = wid + POOL_WAVES * i;
            if (n < N_NODES) {
                const int e0 = rs2[n * KBUK + k], e1 = rs2[n * KBUK + k + 1];
                for (int base = e0; base < e1; base += 64) {
                    const int nn = (e1 - base < 64) ? (e1 - base) : 64;
                    int idx = base + lane;
                    idx = idx < e1 - 1 ? idx : e1 - 1;  // clamp: stay in-bucket
                    int ci = col[idx];
                    for (int j = 0; j < nn; j += 4) {
                        int s[4];
                        unsigned int v[4];
#pragma unroll
                        for (int q = 0; q < 4; q++) {
                            int jj = j + q;
                            jj = jj < nn - 1 ? jj : nn - 1;  // dup = in-bucket row
                            s[q] = __shfl(ci, jj, 64);
                        }
#pragma unroll
                        for (int q = 0; q < 4; q++)
                            v[q] = *(const unsigned int*)(hb + (size_t)s[q] * DIM + c2);
#pragma unroll
                        for (int q = 0; q < 4; q++) {
                            if (j + q < nn) { a0[i] += bflo(v[q]); a1[i] += bfhi(v[q]); }
                        }
                    }
                }
            }
        }
    }

#pragma unroll
    for (int i = 0; i < NPW; i++) {
        int n = wid + POOL_WAVES * i;
        if (n < N_NODES) {
            unsigned short u[2] = {f2bf(a0[i]), f2bf(a1[i])};
            *(unsigned int*)(pooled_b + (size_t)n * DIM + c2) = *(unsigned int*)u;
        }
    }
}

// fused Linear1 -> ReLU -> Linear2 -> BN -> ReLU for a 64-row tile.
// A-fragments loaded straight from bf16 row-major pooled_b (no LDS staging).
__global__ __launch_bounds__(256) void mlp_kernel(
    const unsigned short* __restrict__ pooled_b,
    const unsigned short* __restrict__ wp1,
    const unsigned short* __restrict__ wp2,
    const float* __restrict__ b1,
    const float* __restrict__ b2,
    const float* __restrict__ bnscale,
    const float* __restrict__ bnshift,
    float* __restrict__ h_out,
    unsigned short* __restrict__ hb_out) {
    __shared__ __align__(16) unsigned short zfrag[4][4][64][8];  // z1 shuffle, wave-private
    const int tid = threadIdx.x;
    const int wave = tid >> 6, lane = tid & 63;
    const int m0 = blockIdx.x * 64;
    const int colc = lane & 15;
    const int quad = lane >> 4;
    const int arow = m0 + wave * 16 + colc;
    const int arow_c = arow < N_NODES ? arow : N_NODES - 1;

    bf16x8 a[4];
#pragma unroll
    for (int ks = 0; ks < 4; ks++)
        a[ks] = *(const bf16x8*)(pooled_b + arow_c * DIM + ks * 32 + quad * 8);

    f32x4 acc[8];
#pragma unroll
    for (int nt = 0; nt < 8; nt++) {
        acc[nt] = (f32x4){0.f, 0.f, 0.f, 0.f};
#pragma unroll
        for (int ks = 0; ks < 4; ks++) {
            bf16x8 b = *(const bf16x8*)(wp1 + ((ks * 8 + nt) * 64 + lane) * 8);
            acc[nt] = __builtin_amdgcn_mfma_f32_16x16x32_bf16(a[ks], b, acc[nt], 0, 0, 0);
        }
    }

    // bias + ReLU, write z1 to LDS in A-fragment layout (wave-private region)
#pragma unroll
    for (int nt = 0; nt < 8; nt++) {
        int n = nt * 16 + colc;
        float bias = b1[n];
#pragma unroll
        for (int r = 0; r < 4; r++) {
            float v = acc[nt][r] + bias;
            v = v > 0.f ? v : 0.f;
            int row16 = quad * 4 + r;
            zfrag[wave][n >> 5][(((n >> 3) & 3) << 4) | row16][n & 7] = f2bf(v);
        }
    }

#pragma unroll
    for (int ks = 0; ks < 4; ks++) a[ks] = *(const bf16x8*)(&zfrag[wave][ks][lane][0]);

    f32x4 acc2[8];
#pragma unroll
    for (int nt = 0; nt < 8; nt++) {
        acc2[nt] = (f32x4){0.f, 0.f, 0.f, 0.f};
#pragma unroll
        for (int ks = 0; ks < 4; ks++) {
            bf16x8 b = *(const bf16x8*)(wp2 + ((ks * 8 + nt) * 64 + lane) * 8);
            acc2[nt] = __builtin_amdgcn_mfma_f32_16x16x32_bf16(a[ks], b, acc2[nt], 0, 0, 0);
        }
    }

    // epilogue: +b2, BN, ReLU; nontemporal fp32 out (write-only) + bf16 shadow
#pragma unroll
    for (int nt = 0; nt < 8; nt++) {
        int n = nt * 16 + colc;
        float bias = b2[n];
        float sc = bnscale[n], sh = bnshift[n];
#pragma unroll
        for (int r = 0; r < 4; r++) {
            int row = m0 + wave * 16 + quad * 4 + r;
            if (row < N_NODES) {
                float z = acc2[nt][r] + bias;
                z = z * sc + sh;
                z = z > 0.f ? z : 0.f;
                __builtin_nontemporal_store(z, &h_out[row * DIM + n]);
                hb_out[row * DIM + n] = f2bf(z);
            }
        }
    }
}

// ---- launch --------------------------------------------------------------

extern "C" void kernel_launch(void* const* d_in, const int* in_sizes, int n_in,
                              void* d_out, int out_size, void* d_ws, size_t ws_size,
                              hipStream_t stream) {
    const float* x     = (const float*)d_in[0];
    const int* esrc    = (const int*)d_in[1];
    const int* edst    = (const int*)d_in[2];
    const float* eps   = (const float*)d_in[3];
    const float* W1    = (const float*)d_in[4];
    const float* b1    = (const float*)d_in[5];
    const float* W2    = (const float*)d_in[6];
    const float* b2    = (const float*)d_in[7];
    const float* gam   = (const float*)d_in[8];
    const float* bet   = (const float*)d_in[9];
    const float* bmean = (const float*)d_in[10];
    const float* bvar  = (const float*)d_in[11];
    float* out = (float*)d_out;

    char* ws = (char*)d_ws;
    unsigned short* hb0   = (unsigned short*)(ws);               // 12,800,000 B
    unsigned short* hb1   = (unsigned short*)(ws + 12800000);    // 12,800,000 B
    int*   col        = (int*)  (ws + 25600000);                 //  3,200,000 B
    int*   rs2        = (int*)  (ws + 28800000);                 //    800,004 B
    int*   cursor2    = (int*)  (ws + 29600256);                 //    800,000 B
    int*   cnt2       = (int*)  (ws + 30400256);                 //    800,000 B
    int*   blocksum   = (int*)  (ws + 31200256);                 //      3,328 B
    unsigned short* wpack = (unsigned short*)(ws + 31203584);    //    327,680 B
    float* bnscale    = (float*)(ws + 31531264);                 //      2,560 B
    float* bnshift    = (float*)(ws + 31533824);                 //      2,560 B
    unsigned short* pooled_b = (unsigned short*)(ws + 31536384); // 12,800,000 B

    init_zero_kernel<<<((N_NODES * DIM) / 4 + NB2 + 255) / 256, 256, 0, stream>>>(
        x, out, hb0, cnt2);
    hist_kernel<<<(N_EDGES + 255) / 256, 256, 0, stream>>>(esrc, edst, cnt2);
    scanA_kernel<<<NBLK2, 256, 0, stream>>>(cnt2, blocksum);
    scanB_kernel<<<1, 1024, 0, stream>>>(blocksum, rs2);
    scanC_kernel<<<NBLK2, 256, 0, stream>>>(cnt2, blocksum, rs2, cursor2);
    fill_kernel<<<(N_EDGES + 255) / 256, 256, 0, stream>>>(esrc, edst, cursor2, col);
    prep_kernel<<<(N_LAYERS * 2 * 2048 + N_LAYERS * DIM + 255) / 256, 256, 0, stream>>>(
        W1, W2, wpack, gam, bet, bmean, bvar, bnscale, bnshift);

    const int pool_blocks = POOL_WAVES / 4;      // 2048, all co-resident
    const int mlp_blocks  = (N_NODES + 63) / 64; // 782
    unsigned short* hbuf[2] = {hb0, hb1};
    for (int l = 0; l < N_LAYERS; l++) {
        float* h_next = out + (size_t)(l + 1) * N_NODES * DIM;
        pool_kernel<<<pool_blocks, 256, 0, stream>>>(hbuf[l & 1], rs2, col, eps + l,
                                                     pooled_b);
        mlp_kernel<<<mlp_blocks, 256, 0, stream>>>(
            pooled_b,
            wpack + (size_t)(l * 2) * 16384,
            wpack + (size_t)(l * 2 + 1) * 16384,
            b1 + l * DIM, b2 + l * DIM,
            bnscale + l * DIM, bnshift + l * DIM,
            h_next, hbuf[(l + 1) & 1]);
    }
}

// Round 10
// 509.356 us; speedup vs baseline: 1.2095x; 1.2095x over previous
//
#include <hip/hip_runtime.h>
#include <hip/hip_bf16.h>

#define N_NODES 50000
#define N_EDGES 800000
#define DIM 128
#define N_LAYERS 5
#define BN_EPS 1e-3f
#define NBLK_SCAN ((N_NODES + 255) / 256)  // 196

typedef __attribute__((ext_vector_type(8))) short bf16x8;
typedef __attribute__((ext_vector_type(4))) float f32x4;
typedef __attribute__((ext_vector_type(4))) unsigned int u32x4;
typedef __attribute__((ext_vector_type(2))) unsigned int u32x2;

__device__ __forceinline__ unsigned short f2bf(float f) {
    unsigned int v = __builtin_bit_cast(unsigned int, f);
    v += 0x7fffu + ((v >> 16) & 1u);
    return (unsigned short)(v >> 16);
}
__device__ __forceinline__ float bflo(unsigned int v) {
    return __builtin_bit_cast(float, v << 16);
}
__device__ __forceinline__ float bfhi(unsigned int v) {
    return __builtin_bit_cast(float, v & 0xffff0000u);
}

// ---- setup kernels -------------------------------------------------------

// copy x -> out chunk 0 (fp32) + hb0 (bf16 shadow); also zero cnt[]
__global__ void init_zero_kernel(const float* __restrict__ x, float* __restrict__ out,
                                 unsigned short* __restrict__ hb, int* __restrict__ cnt) {
    int t = blockIdx.x * blockDim.x + threadIdx.x;
    if (t < (N_NODES * DIM) / 4) {
        f32x4 v = ((const f32x4*)x)[t];
        __builtin_nontemporal_store(v, (f32x4*)out + t);
        unsigned short u[4] = {f2bf(v.x), f2bf(v.y), f2bf(v.z), f2bf(v.w)};
        *(u32x2*)(hb + t * 4) = *(u32x2*)u;
    }
    int z = t - (N_NODES * DIM) / 4;
    if (z >= 0 && z < N_NODES) cnt[z] = 0;
}

__global__ void hist_kernel(const int* __restrict__ dst, int* __restrict__ cnt) {
    int e = blockIdx.x * blockDim.x + threadIdx.x;
    if (e < N_EDGES) atomicAdd(&cnt[dst[e]], 1);
}

// parallel scan, 3 dispatches
__global__ __launch_bounds__(256) void scanA_kernel(const int* __restrict__ cnt,
                                                    int* __restrict__ blocksum) {
    const int tid = threadIdx.x, lane = tid & 63, wave = tid >> 6;
    int i = blockIdx.x * 256 + tid;
    int v = (i < N_NODES) ? cnt[i] : 0;
#pragma unroll
    for (int off = 1; off < 64; off <<= 1) v += __shfl_xor(v, off, 64);
    __shared__ int ws[4];
    if (lane == 0) ws[wave] = v;
    __syncthreads();
    if (tid == 0) blocksum[blockIdx.x] = ws[0] + ws[1] + ws[2] + ws[3];
}

__global__ __launch_bounds__(256) void scanB_kernel(int* __restrict__ blocksum,
                                                    int* __restrict__ row_start) {
    __shared__ int s[256];
    const int tid = threadIdx.x;
    int v = (tid < NBLK_SCAN) ? blocksum[tid] : 0;
    s[tid] = v;
    __syncthreads();
#pragma unroll
    for (int off = 1; off < 256; off <<= 1) {
        int t = (tid >= off) ? s[tid - off] : 0;
        __syncthreads();
        s[tid] += t;
        __syncthreads();
    }
    if (tid < NBLK_SCAN) blocksum[tid] = s[tid] - v;  // exclusive block offset
    if (tid == 0) row_start[N_NODES] = N_EDGES;
}

__global__ __launch_bounds__(256) void scanC_kernel(const int* __restrict__ cnt,
                                                    const int* __restrict__ blockoff,
                                                    int* __restrict__ row_start,
                                                    int* __restrict__ cursor) {
    const int tid = threadIdx.x, lane = tid & 63, wave = tid >> 6;
    int i = blockIdx.x * 256 + tid;
    int v = (i < N_NODES) ? cnt[i] : 0;
    int x = v;
#pragma unroll
    for (int off = 1; off < 64; off <<= 1) {
        int t = __shfl_up(x, off, 64);
        if (lane >= off) x += t;
    }
    __shared__ int ws[4];
    if (lane == 63) ws[wave] = x;
    __syncthreads();
    int woff = 0;
    if (wave > 0) woff += ws[0];
    if (wave > 1) woff += ws[1];
    if (wave > 2) woff += ws[2];
    int excl = blockoff[blockIdx.x] + woff + x - v;
    if (i < N_NODES) { row_start[i] = excl; cursor[i] = excl; }
}

__global__ void fill_kernel(const int* __restrict__ src, const int* __restrict__ dst,
                            int* __restrict__ cursor, int* __restrict__ col) {
    int e = blockIdx.x * blockDim.x + threadIdx.x;
    if (e < N_EDGES) {
        int d = dst[e];
        int pos = atomicAdd(&cursor[d], 1);
        col[pos] = src[e];
    }
}

// pack W1/W2 (fp32->bf16) into B-fragment order + fold BN scale/shift
__global__ void prep_kernel(const float* __restrict__ W1, const float* __restrict__ W2,
                            unsigned short* __restrict__ wp,
                            const float* __restrict__ gamma, const float* __restrict__ beta,
                            const float* __restrict__ mean, const float* __restrict__ var,
                            float* __restrict__ scale, float* __restrict__ shift) {
    int t = blockIdx.x * blockDim.x + threadIdx.x;
    if (t < N_LAYERS * 2 * 2048) {
        int mat = t >> 11;
        int r = t & 2047;
        int ks = r >> 9, nt = (r >> 6) & 7, lane = r & 63;
        int layer = mat >> 1;
        const float* W = ((mat & 1) ? W2 : W1) + layer * DIM * DIM;
        int n = nt * 16 + (lane & 15);
        int kb = ks * 32 + (lane >> 4) * 8;
        unsigned short u[8];
#pragma unroll
        for (int j = 0; j < 8; j++) u[j] = f2bf(W[(kb + j) * DIM + n]);
        *(u32x4*)(wp + (size_t)mat * 16384 + ((ks * 8 + nt) * 64 + lane) * 8) = *(u32x4*)u;
    }
    int i = t - N_LAYERS * 2 * 2048;
    if (i >= 0 && i < N_LAYERS * DIM) {
        float sc = gamma[i] * rsqrtf(var[i] + BN_EPS);
        scale[i] = sc;
        shift[i] = beta[i] - mean[i] * sc;
    }
}

// ---- fused per-layer kernel ----------------------------------------------
// 1024-thread block (16 waves) owns 64 nodes.
// Phase 1 (pool): wave w pools nodes m0+4w..m0+4w+3 with the measured-optimal
//   gather shape (64 lanes x 4B = one coalesced 256B row / instr, 8 in
//   flight), accumulating in registers; result -> 16KB LDS tile (XOR-swizzled
//   granules so phase-2 strided reads are conflict-free).
// Phase 2 (mlp): wave (r,c): rows r*16..+15, cols c*32..+31. GEMM1 from LDS,
//   z1 through zfrag (A-fragment layout), GEMM2, BN epilogue.
__global__ __launch_bounds__(1024) void layer_kernel(
    const unsigned short* __restrict__ hb,
    const int* __restrict__ row_start,
    const int* __restrict__ col,
    const float* __restrict__ eps_l,
    const unsigned short* __restrict__ wp1,
    const unsigned short* __restrict__ wp2,
    const float* __restrict__ b1,
    const float* __restrict__ b2,
    const float* __restrict__ bnscale,
    const float* __restrict__ bnshift,
    float* __restrict__ h_out,
    unsigned short* __restrict__ hb_out,
    const int store_hb) {
    __shared__ unsigned int pooled[64 * 64];                     // 16 KB, dword = 2 bf16
    __shared__ __align__(16) unsigned short zfrag[4][4][64][8];  // 16 KB
    const int tid = threadIdx.x;
    const int wave = tid >> 6, lane = tid & 63;
    const int m0 = blockIdx.x * 64;
    const float ev = 1.0f + eps_l[0];

    // ---- phase 1: pool 4 nodes per wave
    for (int i = 0; i < 4; i++) {
        const int lrow = wave * 4 + i;
        const int n = m0 + lrow;
        float a0 = 0.f, a1 = 0.f;
        if (n < N_NODES) {
            unsigned int sv = *(const unsigned int*)(hb + (size_t)n * DIM + lane * 2);
            a0 = ev * bflo(sv);
            a1 = ev * bfhi(sv);
            const int s0 = row_start[n], s1 = row_start[n + 1];
            for (int base = s0; base < s1; base += 64) {
                const int nn = (s1 - base < 64) ? (s1 - base) : 64;
                int ci = (base + lane < s1) ? col[base + lane] : 0;
                for (int j = 0; j < nn; j += 8) {
                    int s[8];
                    unsigned int v[8];
#pragma unroll
                    for (int q = 0; q < 8; q++) s[q] = __shfl(ci, j + q, 64);
#pragma unroll
                    for (int q = 0; q < 8; q++)
                        v[q] = *(const unsigned int*)(hb + (size_t)s[q] * DIM + lane * 2);
#pragma unroll
                    for (int q = 0; q < 8; q++) {
                        if (j + q < nn) { a0 += bflo(v[q]); a1 += bfhi(v[q]); }
                    }
                }
            }
        }
        unsigned short u[2] = {f2bf(a0), f2bf(a1)};
        // swizzled store: granule (lane>>2) ^ (row&15); sub-dword = lane&3
        int g = (lane >> 2) ^ (lrow & 15);
        pooled[lrow * 64 + (g << 2) + (lane & 3)] = *(unsigned int*)u;
    }
    __syncthreads();

    // ---- phase 2: MLP. wave (r,c)
    const int r = wave >> 2, c = wave & 3;
    const int colc = lane & 15, quad = lane >> 4;
    const int lr = r * 16 + colc;  // local A row for this lane

    bf16x8 a[4];
#pragma unroll
    for (int ks = 0; ks < 4; ks++) {
        int g = (ks * 4 + quad) ^ (lr & 15);
        a[ks] = *(const bf16x8*)(&pooled[lr * 64 + (g << 2)]);
    }

    f32x4 acc[2];
#pragma unroll
    for (int q = 0; q < 2; q++) {
        const int nt = c * 2 + q;
        acc[q] = (f32x4){0.f, 0.f, 0.f, 0.f};
#pragma unroll
        for (int ks = 0; ks < 4; ks++) {
            bf16x8 b = *(const bf16x8*)(wp1 + ((ks * 8 + nt) * 64 + lane) * 8);
            acc[q] = __builtin_amdgcn_mfma_f32_16x16x32_bf16(a[ks], b, acc[q], 0, 0, 0);
        }
    }

    // bias + ReLU -> zfrag[r] (wave (r,c) writes exactly ks-slice c: n>>5 == c)
#pragma unroll
    for (int q = 0; q < 2; q++) {
        const int nt = c * 2 + q;
        const int n = nt * 16 + colc;
        float bias = b1[n];
#pragma unroll
        for (int rr = 0; rr < 4; rr++) {
            float v = acc[q][rr] + bias;
            v = v > 0.f ? v : 0.f;
            int row16 = quad * 4 + rr;
            zfrag[r][n >> 5][(((n >> 3) & 3) << 4) | row16][n & 7] = f2bf(v);
        }
    }
    __syncthreads();

#pragma unroll
    for (int ks = 0; ks < 4; ks++) a[ks] = *(const bf16x8*)(&zfrag[r][ks][lane][0]);

    f32x4 acc2[2];
#pragma unroll
    for (int q = 0; q < 2; q++) {
        const int nt = c * 2 + q;
        acc2[q] = (f32x4){0.f, 0.f, 0.f, 0.f};
#pragma unroll
        for (int ks = 0; ks < 4; ks++) {
            bf16x8 b = *(const bf16x8*)(wp2 + ((ks * 8 + nt) * 64 + lane) * 8);
            acc2[q] = __builtin_amdgcn_mfma_f32_16x16x32_bf16(a[ks], b, acc2[q], 0, 0, 0);
        }
    }

    // epilogue: +b2, BN, ReLU; fp32 out + (optional) bf16 shadow
#pragma unroll
    for (int q = 0; q < 2; q++) {
        const int nt = c * 2 + q;
        const int n = nt * 16 + colc;
        float bias = b2[n];
        float sc = bnscale[n], sh = bnshift[n];
#pragma unroll
        for (int rr = 0; rr < 4; rr++) {
            int row = m0 + r * 16 + quad * 4 + rr;
            if (row < N_NODES) {
                float z = acc2[q][rr] + bias;
                z = z * sc + sh;
                z = z > 0.f ? z : 0.f;
                __builtin_nontemporal_store(z, &h_out[(size_t)row * DIM + n]);
                if (store_hb) hb_out[(size_t)row * DIM + n] = f2bf(z);
            }
        }
    }
}

// ---- launch --------------------------------------------------------------

extern "C" void kernel_launch(void* const* d_in, const int* in_sizes, int n_in,
                              void* d_out, int out_size, void* d_ws, size_t ws_size,
                              hipStream_t stream) {
    const float* x     = (const float*)d_in[0];
    const int* esrc    = (const int*)d_in[1];
    const int* edst    = (const int*)d_in[2];
    const float* eps   = (const float*)d_in[3];
    const float* W1    = (const float*)d_in[4];
    const float* b1    = (const float*)d_in[5];
    const float* W2    = (const float*)d_in[6];
    const float* b2    = (const float*)d_in[7];
    const float* gam   = (const float*)d_in[8];
    const float* bet   = (const float*)d_in[9];
    const float* bmean = (const float*)d_in[10];
    const float* bvar  = (const float*)d_in[11];
    float* out = (float*)d_out;

    char* ws = (char*)d_ws;
    unsigned short* hb0   = (unsigned short*)(ws);               // 12,800,000 B
    unsigned short* hb1   = (unsigned short*)(ws + 12800000);    // 12,800,000 B
    int*   col        = (int*)  (ws + 25600000);                 //  3,200,000 B
    int*   row_start  = (int*)  (ws + 28800000);                 //    200,004 B
    int*   cursor     = (int*)  (ws + 29000192);                 //    200,000 B
    int*   cnt        = (int*)  (ws + 29200384);                 //    200,000 B
    int*   blocksum   = (int*)  (ws + 29400576);                 //      1,024 B
    unsigned short* wpack = (unsigned short*)(ws + 29401600);    //    327,680 B
    float* bnscale    = (float*)(ws + 29729280);                 //      2,560 B
    float* bnshift    = (float*)(ws + 29731840);                 //      2,560 B

    init_zero_kernel<<<((N_NODES * DIM) / 4 + N_NODES + 255) / 256, 256, 0, stream>>>(
        x, out, hb0, cnt);
    hist_kernel<<<(N_EDGES + 255) / 256, 256, 0, stream>>>(edst, cnt);
    scanA_kernel<<<NBLK_SCAN, 256, 0, stream>>>(cnt, blocksum);
    scanB_kernel<<<1, 256, 0, stream>>>(blocksum, row_start);
    scanC_kernel<<<NBLK_SCAN, 256, 0, stream>>>(cnt, blocksum, row_start, cursor);
    fill_kernel<<<(N_EDGES + 255) / 256, 256, 0, stream>>>(esrc, edst, cursor, col);
    prep_kernel<<<(N_LAYERS * 2 * 2048 + N_LAYERS * DIM + 255) / 256, 256, 0, stream>>>(
        W1, W2, wpack, gam, bet, bmean, bvar, bnscale, bnshift);

    const int layer_blocks = (N_NODES + 63) / 64;  // 782
    unsigned short* hbuf[2] = {hb0, hb1};
    for (int l = 0; l < N_LAYERS; l++) {
        float* h_next = out + (size_t)(l + 1) * N_NODES * DIM;
        layer_kernel<<<layer_blocks, 1024, 0, stream>>>(
            hbuf[l & 1], row_start, col, eps + l,
            wpack + (size_t)(l * 2) * 16384,
            wpack + (size_t)(l * 2 + 1) * 16384,
            b1 + l * DIM, b2 + l * DIM,
            bnscale + l * DIM, bnshift + l * DIM,
            h_next, hbuf[(l + 1) & 1],
            (l + 1 < N_LAYERS) ? 1 : 0);
    }
}